// Round 2
// baseline (1540.880 us; speedup 1.0000x reference)
//
#include <hip/hip_runtime.h>
#include <hip/hip_bf16.h>

#define IN_DIM  64
#define HID     128
#define OUT_DIM 32

typedef short v8s __attribute__((ext_vector_type(8)));
typedef float v4f __attribute__((ext_vector_type(4)));

__device__ __forceinline__ float swishf(float v) {
    // v * sigmoid(v) with native v_exp / v_rcp
    return __fdividef(v, 1.0f + __expf(-v));
}
__device__ __forceinline__ unsigned pk2(float a, float b) {
    __hip_bfloat162 p = __float22bfloat162_rn(make_float2(a, b));
    return *(unsigned*)&p;
}

// v1 structure (zero main-loop barriers, wave-private 16-row slabs, weights in
// LDS) with two fixes:
//  - 16 waves share ONE weight copy (1024-thr block, 146KB LDS) -> 4 waves/SIMD
//  - XOR-swizzled LDS layouts (byte ^= (row&7)<<4) -> conflict-free b128 reads
__global__ __launch_bounds__(1024, 4)
void subnet_mlp(const float* __restrict__ x,  const float* __restrict__ W1,
                const float* __restrict__ b1, const float* __restrict__ Wh,
                const float* __restrict__ bh, const float* __restrict__ Wo,
                const float* __restrict__ bo, float* __restrict__ out,
                int n_iters)
{
    // swizzled layouts: element (row c, col k) at byte c*rowB + ((2k) ^ ((c&7)<<4))
    __shared__ __align__(16) short sW1[HID * IN_DIM];     // 16 KB  W1^T[c][k]
    __shared__ __align__(16) short sWh[2][HID * HID];     // 64 KB  Wh^T[l][c][k]
    __shared__ __align__(16) short sSlab[16][16 * HID];   // 64 KB  per-wave H[n][c]
    __shared__ float sB1[HID], sBh0[HID], sBh1[HID], sWo[HID];

    const int tid   = threadIdx.x;
    const int o     = blockIdx.x >> 3;    // subnet
    const int slice = blockIdx.x & 7;     // row-slice

    char* const cW1 = (char*)sW1;
    char* const cWh = (char*)sWh;
    char* const cSl = (char*)sSlab;

    // ---------------- one-time staging (bf16, transposed, swizzled) ----------------
    {   // W1^T: 1024 tasks: c = tid&127, k-group kg = tid>>7 (8 k each)
        const int c = tid & 127, kg = tid >> 7;
        const float* p = W1 + ((size_t)o * IN_DIM + kg * 8) * HID + c;
        union { v8s v; unsigned u[4]; } cv;
        #pragma unroll
        for (int j = 0; j < 4; ++j)
            cv.u[j] = pk2(p[(2 * j) * HID], p[(2 * j + 1) * HID]);
        *(v8s*)(cW1 + c * 128 + ((kg * 16) ^ ((c & 7) << 4))) = cv.v;
    }
    #pragma unroll
    for (int r = 0; r < 4; ++r) {   // Wh^T: 4096 tasks
        const int t = tid + r * 1024;
        const int c = t & 127, kg = (t >> 7) & 15, l = t >> 11;
        const float* p = Wh + (((size_t)l * OUT_DIM + o) * HID + kg * 8) * HID + c;
        union { v8s v; unsigned u[4]; } cv;
        #pragma unroll
        for (int j = 0; j < 4; ++j)
            cv.u[j] = pk2(p[(2 * j) * HID], p[(2 * j + 1) * HID]);
        *(v8s*)(cWh + l * 32768 + c * 256 + ((kg * 16) ^ ((c & 7) << 4))) = cv.v;
    }
    if (tid < HID) {
        sB1[tid]  = b1[o * HID + tid];
        sBh0[tid] = bh[o * HID + tid];
        sBh1[tid] = bh[(OUT_DIM + o) * HID + tid];
        sWo[tid]  = Wo[o * HID + tid];
    }
    __syncthreads();   // the ONLY block-wide barrier

    const int lane = tid & 63;
    const int w    = tid >> 6;    // wave id: owns rows [w*16, w*16+16) of each tile
    const int n    = lane & 15;   // fragment row/col index
    const int q    = lane >> 4;   // quad
    const float bo_v = bo[o];

    // loop-invariant swizzled offsets (k-chunk offsets shared by A-reads & B-reads)
    const int swz = (n & 7) << 4;
    int koff[4], wroff[8];
    #pragma unroll
    for (int kc = 0; kc < 4; ++kc) koff[kc] = (kc * 64 + q * 16) ^ swz;
    #pragma unroll
    for (int ct = 0; ct < 8; ++ct) wroff[ct] = (ct * 32 + q * 8) ^ swz;

    char* const myW1 = cW1 + n * 128;             // + imm ct*2048
    char* const myWh = cWh + n * 256;             // + imm l*32768 + ct*4096
    char* const mySl = cSl + w * 4096 + n * 256;

    for (int it = 0; it < n_iters; ++it) {
        const int row = (slice * n_iters + it) * 256 + w * 16 + n;

        // ---- x fragments (B-operand, row-major, k-contiguous) ----
        v8s xb[2];
        #pragma unroll
        for (int kc = 0; kc < 2; ++kc) {
            const float* xp = x + (size_t)row * IN_DIM + kc * 32 + q * 8;
            float4 f0 = *(const float4*)xp;
            float4 f1 = *(const float4*)(xp + 4);
            union { v8s v; unsigned u[4]; } cv;
            cv.u[0] = pk2(f0.x, f0.y); cv.u[1] = pk2(f0.z, f0.w);
            cv.u[2] = pk2(f1.x, f1.y); cv.u[3] = pk2(f1.z, f1.w);
            xb[kc] = cv.v;
        }

        // ================= layer 1: C^T = W1^T @ X^T =================
        v4f acc[8];
        #pragma unroll
        for (int ct = 0; ct < 8; ++ct)           // bias rides the accumulator init
            acc[ct] = *(const v4f*)&sB1[ct * 16 + 4 * q];
        #pragma unroll
        for (int kc = 0; kc < 2; ++kc)
            #pragma unroll
            for (int ct = 0; ct < 8; ++ct) {
                v8s a = *(const v8s*)(myW1 + ct * 2048 + koff[kc]);
                acc[ct] = __builtin_amdgcn_mfma_f32_16x16x32_bf16(a, xb[kc], acc[ct], 0, 0, 0);
            }
        #pragma unroll
        for (int ct = 0; ct < 8; ++ct) {         // swish + packed b64 store
            uint2 pk;
            pk.x = pk2(swishf(acc[ct][0]), swishf(acc[ct][1]));
            pk.y = pk2(swishf(acc[ct][2]), swishf(acc[ct][3]));
            *(uint2*)(mySl + wroff[ct]) = pk;
        }

        // ================= hidden layers =================
        #pragma unroll
        for (int l = 0; l < 2; ++l) {
            v8s hb[4];
            #pragma unroll
            for (int kc = 0; kc < 4; ++kc)       // load ALL B-frags before overwriting slab
                hb[kc] = *(const v8s*)(mySl + koff[kc]);
            const float* bias = l ? sBh1 : sBh0;
            #pragma unroll
            for (int ct = 0; ct < 8; ++ct)
                acc[ct] = *(const v4f*)&bias[ct * 16 + 4 * q];
            #pragma unroll
            for (int kc = 0; kc < 4; ++kc)
                #pragma unroll
                for (int ct = 0; ct < 8; ++ct) {
                    v8s a = *(const v8s*)(myWh + l * 32768 + ct * 4096 + koff[kc]);
                    acc[ct] = __builtin_amdgcn_mfma_f32_16x16x32_bf16(a, hb[kc], acc[ct], 0, 0, 0);
                }
            if (l == 0) {
                #pragma unroll
                for (int ct = 0; ct < 8; ++ct) {
                    uint2 pk;
                    pk.x = pk2(swishf(acc[ct][0]), swishf(acc[ct][1]));
                    pk.y = pk2(swishf(acc[ct][2]), swishf(acc[ct][3]));
                    *(uint2*)(mySl + wroff[ct]) = pk;
                }
            } else {
                // head fused into the epilogue (wo via lane-uniform LDS broadcast)
                float p = 0.0f;
                #pragma unroll
                for (int ct = 0; ct < 8; ++ct) {
                    v4f wo = *(const v4f*)&sWo[ct * 16 + 4 * q];
                    p += swishf(acc[ct][0]) * wo[0];
                    p += swishf(acc[ct][1]) * wo[1];
                    p += swishf(acc[ct][2]) * wo[2];
                    p += swishf(acc[ct][3]) * wo[3];
                }
                p += __shfl_xor(p, 16);          // reduce across the 4 quads
                p += __shfl_xor(p, 32);
                if (lane < 16)
                    out[(size_t)row * OUT_DIM + o] = p + bo_v;
            }
        }
    }
}

extern "C" void kernel_launch(void* const* d_in, const int* in_sizes, int n_in,
                              void* d_out, int out_size, void* d_ws, size_t ws_size,
                              hipStream_t stream) {
    const float* x  = (const float*)d_in[0];
    const float* W1 = (const float*)d_in[1];
    const float* b1 = (const float*)d_in[2];
    const float* Wh = (const float*)d_in[3];
    const float* bh = (const float*)d_in[4];
    const float* Wo = (const float*)d_in[5];
    const float* bo = (const float*)d_in[6];
    float* out = (float*)d_out;

    const int N       = in_sizes[0] / IN_DIM;  // 32768
    const int n_iters = N / (8 * 256);         // 16: 8 slices x 256 rows/iter

    dim3 grid(OUT_DIM * 8);                    // 256 blocks: 32 subnets x 8 slices
    dim3 block(1024);                          // 16 waves share one weight copy
    subnet_mlp<<<grid, block, 0, stream>>>(x, W1, b1, Wh, bh, Wo, bo, out, n_iters);
}

// Round 3
// 1522.095 us; speedup vs baseline: 1.0123x; 1.0123x over previous
//
#include <hip/hip_runtime.h>
#include <hip/hip_bf16.h>

#define IN_DIM  64
#define HID     128
#define OUT_DIM 32

typedef short v8s __attribute__((ext_vector_type(8)));
typedef float v4f __attribute__((ext_vector_type(4)));

__device__ __forceinline__ float swishf(float v) {
    // v * sigmoid(v) with native v_exp / v_rcp
    return __fdividef(v, 1.0f + __expf(-v));
}
__device__ __forceinline__ unsigned pk2(float a, float b) {
    __hip_bfloat162 p = __float22bfloat162_rn(make_float2(a, b));
    return *(unsigned*)&p;
}

// Channel-permuted weight staging: tile T, row R holds physical channel
//   ch(T,R) = 32*(T>>1) + 8*(R>>2) + 4*(T&1) + (R&3)
// With C^T-GEMM (C col = n, C row = 4q+j), lane (n,q) then ends each layer
// holding channels {32*kc + 8*q + s} in its packed output registers -- which
// IS the B-operand k-slot layout of the NEXT layer's MFMA. Layer transitions
// are pure register renames: no LDS slab, no shuffles, no barriers.
// LDS = weights only = exactly 80 KB -> 2 blocks/CU -> 4 waves/SIMD.
__global__ __launch_bounds__(512, 4)
void subnet_mlp(const float* __restrict__ x,  const float* __restrict__ W1,
                const float* __restrict__ b1, const float* __restrict__ Wh,
                const float* __restrict__ bh, const float* __restrict__ Wo,
                const float* __restrict__ bo, float* __restrict__ out,
                int n_iters)
{
    // swizzled: row R, 16B-slot kg stored at slot kg ^ (R&7)
    __shared__ __align__(16) short sW1[8 * 16 * 64];       // 16 KB, 8 tiles
    __shared__ __align__(16) short sWh[2 * 8 * 16 * 128];  // 64 KB, 2 layers
    // total 81920 B exactly -> two blocks co-resident per CU

    const int tid   = threadIdx.x;
    const int o     = blockIdx.x >> 4;    // subnet
    const int slice = blockIdx.x & 15;    // row-slice

    char* const cW1 = (char*)sW1;
    char* const cWh = (char*)sWh;

    // ---------------- one-time staging (bf16, permuted, swizzled) ----------------
    #pragma unroll
    for (int r = 0; r < 2; ++r) {          // W1: 1024 tasks (T,R,kg)
        const int t = tid + r * 512;
        const int R = t & 15, T = (t >> 4) & 7, kg = t >> 7;          // kg:0..7
        const int c = 32 * (T >> 1) + 8 * (R >> 2) + 4 * (T & 1) + (R & 3);
        const float* p = W1 + ((size_t)o * IN_DIM + kg * 8) * HID + c;
        union { v8s v; unsigned u[4]; } cv;
        #pragma unroll
        for (int j = 0; j < 4; ++j)
            cv.u[j] = pk2(p[(2 * j) * HID], p[(2 * j + 1) * HID]);
        *(v8s*)(cW1 + T * 2048 + R * 128 + ((kg * 16) ^ ((R & 7) << 4))) = cv.v;
    }
    #pragma unroll
    for (int r = 0; r < 8; ++r) {          // Wh: 4096 tasks (l,T,R,kg)
        const int t = tid + r * 512;
        const int R = t & 15, T = (t >> 4) & 7, kg = (t >> 7) & 15, l = t >> 11;
        const int c = 32 * (T >> 1) + 8 * (R >> 2) + 4 * (T & 1) + (R & 3);
        const float* p = Wh + (((size_t)l * OUT_DIM + o) * HID + kg * 8) * HID + c;
        union { v8s v; unsigned u[4]; } cv;
        #pragma unroll
        for (int j = 0; j < 4; ++j)
            cv.u[j] = pk2(p[(2 * j) * HID], p[(2 * j + 1) * HID]);
        *(v8s*)(cWh + l * 32768 + T * 4096 + R * 256 + ((kg * 16) ^ ((R & 7) << 4))) = cv.v;
    }
    __syncthreads();   // the ONLY block-wide barrier

    const int lane = tid & 63;
    const int w    = tid >> 6;    // wave id: owns rows [w*16, w*16+16)
    const int n    = lane & 15;   // fragment row/col index
    const int q    = lane >> 4;   // quad
    const float bo_v = bo[o];

    // loop-invariant swizzled k-slot byte offsets
    int kW1[2], kWh[4];
    #pragma unroll
    for (int kc = 0; kc < 2; ++kc) kW1[kc] = ((4 * kc + q) ^ (n & 7)) << 4;
    #pragma unroll
    for (int kc = 0; kc < 4; ++kc) kWh[kc] = ((4 * kc + q) ^ (n & 7)) << 4;

    const char* const myW1 = cW1 + n * 128;   // + imm T*2048
    const char* const myWh = cWh + n * 256;   // + imm l*32768 + T*4096
    // per-lane bias/head pointers: element for tile T, j = base + 32*(T>>1)+4*(T&1)+j
    const float* const bp1  = b1 + o * HID + 8 * q;
    const float* const bph0 = bh + o * HID + 8 * q;
    const float* const bph1 = bh + (OUT_DIM + o) * HID + 8 * q;
    const float* const wop  = Wo + o * HID + 8 * q;

    for (int it = 0; it < n_iters; ++it) {
        const int row = (slice * n_iters + it) * 128 + w * 16 + n;

        // ---- x fragments (B-operand, row-major, k-contiguous) ----
        v8s xb[2];
        #pragma unroll
        for (int kc = 0; kc < 2; ++kc) {
            const float* xp = x + (size_t)row * IN_DIM + kc * 32 + q * 8;
            float4 f0 = *(const float4*)xp;
            float4 f1 = *(const float4*)(xp + 4);
            union { v8s v; unsigned u[4]; } cv;
            cv.u[0] = pk2(f0.x, f0.y); cv.u[1] = pk2(f0.z, f0.w);
            cv.u[2] = pk2(f1.x, f1.y); cv.u[3] = pk2(f1.z, f1.w);
            xb[kc] = cv.v;
        }

        // ================= layer 1: C^T = W1^T @ X^T =================
        v4f acc[8];
        #pragma unroll
        for (int T = 0; T < 8; ++T)      // bias rides the accumulator init (L1-cached)
            acc[T] = *(const v4f*)(bp1 + 32 * (T >> 1) + 4 * (T & 1));
        #pragma unroll
        for (int kc = 0; kc < 2; ++kc)
            #pragma unroll
            for (int T = 0; T < 8; ++T) {
                v8s a = *(const v8s*)(myW1 + T * 2048 + kW1[kc]);
                acc[T] = __builtin_amdgcn_mfma_f32_16x16x32_bf16(a, xb[kc], acc[T], 0, 0, 0);
            }
        unsigned pkx[8], pky[8];         // packed H: register-local layer handoff
        #pragma unroll
        for (int T = 0; T < 8; ++T) {
            pkx[T] = pk2(swishf(acc[T][0]), swishf(acc[T][1]));
            pky[T] = pk2(swishf(acc[T][2]), swishf(acc[T][3]));
        }

        // ================= hidden layers =================
        #pragma unroll
        for (int l = 0; l < 2; ++l) {
            v8s hb[4];                   // pure register renames
            #pragma unroll
            for (int kc = 0; kc < 4; ++kc) {
                union { v8s v; unsigned u[4]; } b;
                b.u[0] = pkx[2 * kc];     b.u[1] = pky[2 * kc];
                b.u[2] = pkx[2 * kc + 1]; b.u[3] = pky[2 * kc + 1];
                hb[kc] = b.v;
            }
            const float* bp = l ? bph1 : bph0;
            #pragma unroll
            for (int T = 0; T < 8; ++T)
                acc[T] = *(const v4f*)(bp + 32 * (T >> 1) + 4 * (T & 1));
            #pragma unroll
            for (int kc = 0; kc < 4; ++kc)
                #pragma unroll
                for (int T = 0; T < 8; ++T) {
                    v8s a = *(const v8s*)(myWh + l * 32768 + T * 4096 + kWh[kc]);
                    acc[T] = __builtin_amdgcn_mfma_f32_16x16x32_bf16(a, hb[kc], acc[T], 0, 0, 0);
                }
            if (l == 0) {
                #pragma unroll
                for (int T = 0; T < 8; ++T) {
                    pkx[T] = pk2(swishf(acc[T][0]), swishf(acc[T][1]));
                    pky[T] = pk2(swishf(acc[T][2]), swishf(acc[T][3]));
                }
            } else {
                // head fused into the epilogue (wo v4f loads are L1-resident)
                float p = 0.0f;
                #pragma unroll
                for (int T = 0; T < 8; ++T) {
                    v4f wo = *(const v4f*)(wop + 32 * (T >> 1) + 4 * (T & 1));
                    p += swishf(acc[T][0]) * wo[0];
                    p += swishf(acc[T][1]) * wo[1];
                    p += swishf(acc[T][2]) * wo[2];
                    p += swishf(acc[T][3]) * wo[3];
                }
                p += __shfl_xor(p, 16);          // reduce across the 4 quads
                p += __shfl_xor(p, 32);
                if (lane < 16)
                    out[(size_t)row * OUT_DIM + o] = p + bo_v;
            }
        }
    }
}

extern "C" void kernel_launch(void* const* d_in, const int* in_sizes, int n_in,
                              void* d_out, int out_size, void* d_ws, size_t ws_size,
                              hipStream_t stream) {
    const float* x  = (const float*)d_in[0];
    const float* W1 = (const float*)d_in[1];
    const float* b1 = (const float*)d_in[2];
    const float* Wh = (const float*)d_in[3];
    const float* bh = (const float*)d_in[4];
    const float* Wo = (const float*)d_in[5];
    const float* bo = (const float*)d_in[6];
    float* out = (float*)d_out;

    const int N       = in_sizes[0] / IN_DIM;  // 32768
    const int n_iters = N / (16 * 128);        // 16: 16 slices x 128 rows/iter

    dim3 grid(OUT_DIM * 16);                   // 512 blocks: 32 subnets x 16 slices
    dim3 block(512);                           // 8 waves; 80KB LDS -> 2 blocks/CU
    subnet_mlp<<<grid, block, 0, stream>>>(x, W1, b1, Wh, bh, Wo, bo, out, n_iters);
}

// Round 4
// 767.567 us; speedup vs baseline: 2.0075x; 1.9830x over previous
//
#include <hip/hip_runtime.h>
#include <hip/hip_bf16.h>

#define IN_DIM  64
#define HID     128
#define OUT_DIM 32

typedef short v8s __attribute__((ext_vector_type(8)));
typedef float v4f __attribute__((ext_vector_type(4)));

__device__ __forceinline__ float swishf(float v) {
    // v * sigmoid(v) with native v_exp / v_rcp
    return __fdividef(v, 1.0f + __expf(-v));
}
__device__ __forceinline__ unsigned pk2(float a, float b) {
    __hip_bfloat162 p = __float22bfloat162_rn(make_float2(a, b));
    return *(unsigned*)&p;
}

// Channel-permuted weight staging: tile T, row R holds physical channel
//   ch(T,R) = 32*(T>>1) + 8*(R>>2) + 4*(T&1) + (R&3)
// With C^T-GEMM (C col = n, C row = 4q+j), lane (n,q) then ends each layer
// holding channels {32*kc + 8*q + s} in its packed output registers -- which
// IS the B-operand k-slot layout of the NEXT layer's MFMA. Layer transitions
// are pure register renames: no LDS slab, no shuffles, no barriers.
// LDS = weights only = exactly 80 KB -> 2 blocks/CU -> 4 waves/SIMD.
//
// __launch_bounds__ 2nd arg behaves as CUDA min-BLOCKS-per-CU on this
// toolchain (measured: (512,4)/(1024,4) -> 64-VGPR cap + 3GB scratch spill;
// (512,2) -> 88 VGPRs, clean). (512,2) = 16 waves/CU = 128-VGPR cap.
__global__ __launch_bounds__(512, 2)
void subnet_mlp(const float* __restrict__ x,  const float* __restrict__ W1,
                const float* __restrict__ b1, const float* __restrict__ Wh,
                const float* __restrict__ bh, const float* __restrict__ Wo,
                const float* __restrict__ bo, float* __restrict__ out,
                int n_iters)
{
    // swizzled: row R, 16B-slot kg stored at slot kg ^ (R&7)
    __shared__ __align__(16) short sW1[8 * 16 * 64];       // 16 KB, 8 tiles
    __shared__ __align__(16) short sWh[2 * 8 * 16 * 128];  // 64 KB, 2 layers
    // total 81920 B exactly -> two blocks co-resident per CU

    const int tid   = threadIdx.x;
    const int o     = blockIdx.x >> 4;    // subnet
    const int slice = blockIdx.x & 15;    // row-slice

    char* const cW1 = (char*)sW1;
    char* const cWh = (char*)sWh;

    // ---------------- one-time staging (bf16, permuted, swizzled) ----------------
    #pragma unroll
    for (int r = 0; r < 2; ++r) {          // W1: 1024 tasks (T,R,kg)
        const int t = tid + r * 512;
        const int R = t & 15, T = (t >> 4) & 7, kg = t >> 7;          // kg:0..7
        const int c = 32 * (T >> 1) + 8 * (R >> 2) + 4 * (T & 1) + (R & 3);
        const float* p = W1 + ((size_t)o * IN_DIM + kg * 8) * HID + c;
        union { v8s v; unsigned u[4]; } cv;
        #pragma unroll
        for (int j = 0; j < 4; ++j)
            cv.u[j] = pk2(p[(2 * j) * HID], p[(2 * j + 1) * HID]);
        *(v8s*)(cW1 + T * 2048 + R * 128 + ((kg * 16) ^ ((R & 7) << 4))) = cv.v;
    }
    #pragma unroll
    for (int r = 0; r < 8; ++r) {          // Wh: 4096 tasks (l,T,R,kg)
        const int t = tid + r * 512;
        const int R = t & 15, T = (t >> 4) & 7, kg = (t >> 7) & 15, l = t >> 11;
        const int c = 32 * (T >> 1) + 8 * (R >> 2) + 4 * (T & 1) + (R & 3);
        const float* p = Wh + (((size_t)l * OUT_DIM + o) * HID + kg * 8) * HID + c;
        union { v8s v; unsigned u[4]; } cv;
        #pragma unroll
        for (int j = 0; j < 4; ++j)
            cv.u[j] = pk2(p[(2 * j) * HID], p[(2 * j + 1) * HID]);
        *(v8s*)(cWh + l * 32768 + T * 4096 + R * 256 + ((kg * 16) ^ ((R & 7) << 4))) = cv.v;
    }
    __syncthreads();   // the ONLY block-wide barrier

    const int lane = tid & 63;
    const int w    = tid >> 6;    // wave id: owns rows [w*16, w*16+16)
    const int n    = lane & 15;   // fragment row/col index
    const int q    = lane >> 4;   // quad
    const float bo_v = bo[o];

    // loop-invariant swizzled k-slot byte offsets
    int kW1[2], kWh[4];
    #pragma unroll
    for (int kc = 0; kc < 2; ++kc) kW1[kc] = ((4 * kc + q) ^ (n & 7)) << 4;
    #pragma unroll
    for (int kc = 0; kc < 4; ++kc) kWh[kc] = ((4 * kc + q) ^ (n & 7)) << 4;

    const char* const myW1 = cW1 + n * 128;   // + imm T*2048
    const char* const myWh = cWh + n * 256;   // + imm l*32768 + T*4096
    // per-lane bias/head pointers: element for tile T, j = base + 32*(T>>1)+4*(T&1)+j
    const float* const bp1  = b1 + o * HID + 8 * q;
    const float* const bph0 = bh + o * HID + 8 * q;
    const float* const bph1 = bh + (OUT_DIM + o) * HID + 8 * q;
    const float* const wop  = Wo + o * HID + 8 * q;

    for (int it = 0; it < n_iters; ++it) {
        const int row = (slice * n_iters + it) * 128 + w * 16 + n;

        // ---- x fragments (B-operand, row-major, k-contiguous) ----
        v8s xb[2];
        #pragma unroll
        for (int kc = 0; kc < 2; ++kc) {
            const float* xp = x + (size_t)row * IN_DIM + kc * 32 + q * 8;
            float4 f0 = *(const float4*)xp;
            float4 f1 = *(const float4*)(xp + 4);
            union { v8s v; unsigned u[4]; } cv;
            cv.u[0] = pk2(f0.x, f0.y); cv.u[1] = pk2(f0.z, f0.w);
            cv.u[2] = pk2(f1.x, f1.y); cv.u[3] = pk2(f1.z, f1.w);
            xb[kc] = cv.v;
        }

        // ================= layer 1: C^T = W1^T @ X^T =================
        v4f acc[8];
        #pragma unroll
        for (int T = 0; T < 8; ++T)      // bias rides the accumulator init (L1-cached)
            acc[T] = *(const v4f*)(bp1 + 32 * (T >> 1) + 4 * (T & 1));
        #pragma unroll
        for (int kc = 0; kc < 2; ++kc)
            #pragma unroll
            for (int T = 0; T < 8; ++T) {
                v8s a = *(const v8s*)(myW1 + T * 2048 + kW1[kc]);
                acc[T] = __builtin_amdgcn_mfma_f32_16x16x32_bf16(a, xb[kc], acc[T], 0, 0, 0);
            }
        unsigned pkx[8], pky[8];         // packed H: register-local layer handoff
        #pragma unroll
        for (int T = 0; T < 8; ++T) {
            pkx[T] = pk2(swishf(acc[T][0]), swishf(acc[T][1]));
            pky[T] = pk2(swishf(acc[T][2]), swishf(acc[T][3]));
        }

        // ================= hidden layers =================
        #pragma unroll
        for (int l = 0; l < 2; ++l) {
            v8s hb[4];                   // pure register renames
            #pragma unroll
            for (int kc = 0; kc < 4; ++kc) {
                union { v8s v; unsigned u[4]; } b;
                b.u[0] = pkx[2 * kc];     b.u[1] = pky[2 * kc];
                b.u[2] = pkx[2 * kc + 1]; b.u[3] = pky[2 * kc + 1];
                hb[kc] = b.v;
            }
            const float* bp = l ? bph1 : bph0;
            #pragma unroll
            for (int T = 0; T < 8; ++T)
                acc[T] = *(const v4f*)(bp + 32 * (T >> 1) + 4 * (T & 1));
            #pragma unroll
            for (int kc = 0; kc < 4; ++kc)
                #pragma unroll
                for (int T = 0; T < 8; ++T) {
                    v8s a = *(const v8s*)(myWh + l * 32768 + T * 4096 + kWh[kc]);
                    acc[T] = __builtin_amdgcn_mfma_f32_16x16x32_bf16(a, hb[kc], acc[T], 0, 0, 0);
                }
            if (l == 0) {
                #pragma unroll
                for (int T = 0; T < 8; ++T) {
                    pkx[T] = pk2(swishf(acc[T][0]), swishf(acc[T][1]));
                    pky[T] = pk2(swishf(acc[T][2]), swishf(acc[T][3]));
                }
            } else {
                // head fused into the epilogue (wo v4f loads are L1-resident)
                float p = 0.0f;
                #pragma unroll
                for (int T = 0; T < 8; ++T) {
                    v4f wo = *(const v4f*)(wop + 32 * (T >> 1) + 4 * (T & 1));
                    p += swishf(acc[T][0]) * wo[0];
                    p += swishf(acc[T][1]) * wo[1];
                    p += swishf(acc[T][2]) * wo[2];
                    p += swishf(acc[T][3]) * wo[3];
                }
                p += __shfl_xor(p, 16);          // reduce across the 4 quads
                p += __shfl_xor(p, 32);
                if (lane < 16)
                    out[(size_t)row * OUT_DIM + o] = p + bo_v;
            }
        }
    }
}

extern "C" void kernel_launch(void* const* d_in, const int* in_sizes, int n_in,
                              void* d_out, int out_size, void* d_ws, size_t ws_size,
                              hipStream_t stream) {
    const float* x  = (const float*)d_in[0];
    const float* W1 = (const float*)d_in[1];
    const float* b1 = (const float*)d_in[2];
    const float* Wh = (const float*)d_in[3];
    const float* bh = (const float*)d_in[4];
    const float* Wo = (const float*)d_in[5];
    const float* bo = (const float*)d_in[6];
    float* out = (float*)d_out;

    const int N       = in_sizes[0] / IN_DIM;  // 32768
    const int n_iters = N / (16 * 128);        // 16: 16 slices x 128 rows/iter

    dim3 grid(OUT_DIM * 16);                   // 512 blocks: 32 subnets x 16 slices
    dim3 block(512);                           // 8 waves; 80KB LDS -> 2 blocks/CU
    subnet_mlp<<<grid, block, 0, stream>>>(x, W1, b1, Wh, bh, Wo, bo, out, n_iters);
}

// Round 5
// 293.834 us; speedup vs baseline: 5.2440x; 2.6122x over previous
//
#include <hip/hip_runtime.h>
#include <hip/hip_bf16.h>

#define IN_DIM  64
#define HID     128
#define OUT_DIM 32

typedef short    v8s __attribute__((ext_vector_type(8)));
typedef float    v4f __attribute__((ext_vector_type(4)));
typedef unsigned v4u __attribute__((ext_vector_type(4)));

__device__ __forceinline__ float swishf(float v) {
    // v * sigmoid(v) with native v_exp / v_rcp
    return __fdividef(v, 1.0f + __expf(-v));
}
__device__ __forceinline__ unsigned pk2(float a, float b) {
    __hip_bfloat162 p = __float22bfloat162_rn(make_float2(a, b));
    return *(unsigned*)&p;
}

// Channel-permuted weight staging: tile T, row R holds physical channel
//   ch(T,R) = 32*(T>>1) + 8*(R>>2) + 4*(T&1) + (R&3)
// so each layer's MFMA C-output registers ARE the next layer's B-operand
// fragments (register-local handoff; verified R3/R4, absmax unchanged).
//
// R4 lesson: with no LDS stores in the main loop, LLVM hoists ALL
// loop-invariant LDS/global loads (weights + biases) -> >128 regs -> 2GB
// scratch spill. Fix: biases live in LDS, and every LDS base gets an
// opaque zero offset re-laundered EACH iteration (asm "+v") so no load is
// provably invariant. Weights are re-read from LDS per iter by design
// (29 KB/CU/iter, trivial vs 128 B/cy LDS BW).
//
// Occupancy: one 1024-thread block per CU (82 KB LDS), 16 waves sharing one
// weight copy -> 4 waves/SIMD (2x v0). Zero main-loop barriers.
__global__ __launch_bounds__(1024, 1)
void subnet_mlp(const float* __restrict__ x,  const float* __restrict__ W1,
                const float* __restrict__ b1, const float* __restrict__ Wh,
                const float* __restrict__ bh, const float* __restrict__ Wo,
                const float* __restrict__ bo, float* __restrict__ out,
                int n_iters)
{
    // swizzled: row R, 16B-slot kg stored at slot kg ^ (R&7)
    __shared__ __align__(16) short sW1[8 * 16 * 64];       // 16 KB, 8 tiles
    __shared__ __align__(16) short sWh[2 * 8 * 16 * 128];  // 64 KB, 2 layers
    __shared__ __align__(16) float sBias[512];             // 2 KB: b1|bh0|bh1|wo

    const int tid   = threadIdx.x;
    const int o     = blockIdx.x >> 3;    // subnet
    const int slice = blockIdx.x & 7;     // row-slice

    char* const cW1 = (char*)sW1;
    char* const cWh = (char*)sWh;
    char* const cB  = (char*)sBias;

    // ---------------- one-time staging (bf16, permuted, swizzled) ----------------
    {   // W1: exactly 1024 tasks (T,R,kg)
        const int R = tid & 15, T = (tid >> 4) & 7, kg = tid >> 7;    // kg:0..7
        const int c = 32 * (T >> 1) + 8 * (R >> 2) + 4 * (T & 1) + (R & 3);
        const float* p = W1 + ((size_t)o * IN_DIM + kg * 8) * HID + c;
        union { v8s v; unsigned u[4]; } cv;
        #pragma unroll
        for (int j = 0; j < 4; ++j)
            cv.u[j] = pk2(p[(2 * j) * HID], p[(2 * j + 1) * HID]);
        *(v8s*)(cW1 + T * 2048 + R * 128 + ((kg * 16) ^ ((R & 7) << 4))) = cv.v;
    }
    #pragma unroll
    for (int r = 0; r < 4; ++r) {          // Wh: 4096 tasks (l,T,R,kg)
        const int t = tid + r * 1024;
        const int R = t & 15, T = (t >> 4) & 7, kg = (t >> 7) & 15, l = t >> 11;
        const int c = 32 * (T >> 1) + 8 * (R >> 2) + 4 * (T & 1) + (R & 3);
        const float* p = Wh + (((size_t)l * OUT_DIM + o) * HID + kg * 8) * HID + c;
        union { v8s v; unsigned u[4]; } cv;
        #pragma unroll
        for (int j = 0; j < 4; ++j)
            cv.u[j] = pk2(p[(2 * j) * HID], p[(2 * j + 1) * HID]);
        *(v8s*)(cWh + l * 32768 + T * 4096 + R * 256 + ((kg * 16) ^ ((R & 7) << 4))) = cv.v;
    }
    if (tid < 512) {                       // biases + head weights
        const int idx = tid & 127, seg = tid >> 7;
        float v;
        if      (seg == 0) v = b1[o * HID + idx];
        else if (seg == 1) v = bh[o * HID + idx];
        else if (seg == 2) v = bh[(OUT_DIM + o) * HID + idx];
        else               v = Wo[o * HID + idx];
        sBias[tid] = v;
    }
    __syncthreads();   // the ONLY block-wide barrier

    const int lane = tid & 63;
    const int w    = tid >> 6;    // wave id 0..15: owns rows [w*16, w*16+16)
    const int n    = lane & 15;   // fragment row/col index
    const int q    = lane >> 4;   // quad
    const float bo_v = bo[o];

    // loop-invariant swizzled k-slot byte offsets
    int kW1[2], kWh[4];
    #pragma unroll
    for (int kc = 0; kc < 2; ++kc) kW1[kc] = ((4 * kc + q) ^ (n & 7)) << 4;
    #pragma unroll
    for (int kc = 0; kc < 4; ++kc) kWh[kc] = ((4 * kc + q) ^ (n & 7)) << 4;

    const int w1base = n * 128;
    const int whbase = n * 256;
    const int bbase  = 32 * q;    // bias element 8q (byte)

    for (int it = 0; it < n_iters; ++it) {
        // opaque zero, re-laundered each iteration: defeats LICM on LDS loads
        unsigned z = 0;
        asm volatile("" : "+v"(z));
        const char* const W1p = cW1 + w1base + z;   // + imm T*2048 + kW1[kc]
        const char* const Whp = cWh + whbase + z;   // + imm l*32768 + T*4096 + kWh[kc]
        const char* const Bp  = cB  + bbase  + z;   // + imm seg*512 + 128*(T>>1)+16*(T&1)

        const int row = (slice * n_iters + it) * 256 + w * 16 + n;

        // ---- x fragments (B-operand, row-major, k-contiguous) ----
        v8s xb[2];
        #pragma unroll
        for (int kc = 0; kc < 2; ++kc) {
            const float* xp = x + (size_t)row * IN_DIM + kc * 32 + q * 8;
            float4 f0 = *(const float4*)xp;
            float4 f1 = *(const float4*)(xp + 4);
            union { v8s v; unsigned u[4]; } cv;
            cv.u[0] = pk2(f0.x, f0.y); cv.u[1] = pk2(f0.z, f0.w);
            cv.u[2] = pk2(f1.x, f1.y); cv.u[3] = pk2(f1.z, f1.w);
            xb[kc] = cv.v;
        }

        // ================= layer 1: C^T = W1^T @ X^T =================
        v4f acc[8];
        #pragma unroll
        for (int T = 0; T < 8; ++T)      // bias rides the accumulator init (LDS broadcast)
            acc[T] = *(const v4f*)(Bp + 128 * (T >> 1) + 16 * (T & 1));
        #pragma unroll
        for (int kc = 0; kc < 2; ++kc)
            #pragma unroll
            for (int T = 0; T < 8; ++T) {
                v8s a = *(const v8s*)(W1p + T * 2048 + kW1[kc]);
                acc[T] = __builtin_amdgcn_mfma_f32_16x16x32_bf16(a, xb[kc], acc[T], 0, 0, 0);
            }
        // packed H, filled directly in next-layer B-operand order (k-slot s:
        // T=2kc+hi gives s=4*hi+j) -- register-local layer handoff
        unsigned h[16];
        #pragma unroll
        for (int T = 0; T < 8; ++T) {
            h[(T >> 1) * 4 + 2 * (T & 1)]     = pk2(swishf(acc[T][0]), swishf(acc[T][1]));
            h[(T >> 1) * 4 + 2 * (T & 1) + 1] = pk2(swishf(acc[T][2]), swishf(acc[T][3]));
        }

        // ================= hidden layers =================
        #pragma unroll
        for (int l = 0; l < 2; ++l) {
            #pragma unroll
            for (int T = 0; T < 8; ++T)
                acc[T] = *(const v4f*)(Bp + 512 + l * 512 + 128 * (T >> 1) + 16 * (T & 1));
            #pragma unroll
            for (int kc = 0; kc < 4; ++kc) {
                v4u tu = { h[kc * 4 + 0], h[kc * 4 + 1], h[kc * 4 + 2], h[kc * 4 + 3] };
                v8s hbv = __builtin_bit_cast(v8s, tu);
                #pragma unroll
                for (int T = 0; T < 8; ++T) {
                    v8s a = *(const v8s*)(Whp + l * 32768 + T * 4096 + kWh[kc]);
                    acc[T] = __builtin_amdgcn_mfma_f32_16x16x32_bf16(a, hbv, acc[T], 0, 0, 0);
                }
            }
            if (l == 0) {
                #pragma unroll
                for (int T = 0; T < 8; ++T) {
                    h[(T >> 1) * 4 + 2 * (T & 1)]     = pk2(swishf(acc[T][0]), swishf(acc[T][1]));
                    h[(T >> 1) * 4 + 2 * (T & 1) + 1] = pk2(swishf(acc[T][2]), swishf(acc[T][3]));
                }
            } else {
                // head fused into the epilogue (wo via LDS broadcast)
                float p = 0.0f;
                #pragma unroll
                for (int T = 0; T < 8; ++T) {
                    v4f wo = *(const v4f*)(Bp + 1536 + 128 * (T >> 1) + 16 * (T & 1));
                    p += swishf(acc[T][0]) * wo[0];
                    p += swishf(acc[T][1]) * wo[1];
                    p += swishf(acc[T][2]) * wo[2];
                    p += swishf(acc[T][3]) * wo[3];
                }
                p += __shfl_xor(p, 16);          // reduce across the 4 quads
                p += __shfl_xor(p, 32);
                if (lane < 16)
                    out[(size_t)row * OUT_DIM + o] = p + bo_v;
            }
        }
    }
}

extern "C" void kernel_launch(void* const* d_in, const int* in_sizes, int n_in,
                              void* d_out, int out_size, void* d_ws, size_t ws_size,
                              hipStream_t stream) {
    const float* x  = (const float*)d_in[0];
    const float* W1 = (const float*)d_in[1];
    const float* b1 = (const float*)d_in[2];
    const float* Wh = (const float*)d_in[3];
    const float* bh = (const float*)d_in[4];
    const float* Wo = (const float*)d_in[5];
    const float* bo = (const float*)d_in[6];
    float* out = (float*)d_out;

    const int N       = in_sizes[0] / IN_DIM;  // 32768
    const int n_iters = N / (8 * 256);         // 16: 8 slices x 256 rows/iter

    dim3 grid(OUT_DIM * 8);                    // 256 blocks = one per CU
    dim3 block(1024);                          // 16 waves share one weight copy
    subnet_mlp<<<grid, block, 0, stream>>>(x, W1, b1, Wh, bh, Wo, bo, out, n_iters);
}